// Round 1
// baseline (176.268 us; speedup 1.0000x reference)
//
#include <hip/hip_runtime.h>

// SOM update, M=N=512, DIM=256, NITER=100, ALPHA=0.3, SIGMA=256.
// locations[row] = (row / 512, row % 512)

#define MN   (512 * 512)
#define DIMC 256
#define NCOL 512

// ---------------- kernel 0: init scratch ----------------
__global__ void som_init_ws(unsigned long long* __restrict__ ws) {
    *ws = 0xFFFFFFFFFFFFFFFFull;
}

// ---------------- kernel 1: BMU argmin ----------------
// One wave (64 lanes) per row; lane l loads float4 at row*256 + l*4.
// Squared distance (sqrt skipped: monotonic). Packed-key atomicMin for
// global argmin with first-occurrence tie-break.
__global__ __launch_bounds__(256) void som_bmu_kernel(
        const float* __restrict__ x,
        const float* __restrict__ w,
        unsigned long long* __restrict__ ws) {
    const int lane        = threadIdx.x & 63;
    const int waveInBlock = threadIdx.x >> 6;
    const int wavesPerBlk = blockDim.x >> 6;      // 4
    const int waveId      = blockIdx.x * wavesPerBlk + waveInBlock;
    const int nWaves      = gridDim.x * wavesPerBlk;

    // x fragment for this lane (reused across all rows)
    const float4 xv = reinterpret_cast<const float4*>(x)[lane];

    float bestD  = 3.4e38f;
    int   bestRow = 0;

    for (int row = waveId; row < MN; row += nWaves) {
        const float4 wv =
            reinterpret_cast<const float4*>(w + (size_t)row * DIMC)[lane];
        const float d0 = xv.x - wv.x;
        const float d1 = xv.y - wv.y;
        const float d2 = xv.z - wv.z;
        const float d3 = xv.w - wv.w;
        float s = d0 * d0 + d1 * d1 + d2 * d2 + d3 * d3;
        // wave-wide sum (64 lanes)
        #pragma unroll
        for (int off = 32; off > 0; off >>= 1) s += __shfl_down(s, off);
        // lane 0 holds the row's squared distance
        if (lane == 0 && s < bestD) { bestD = s; bestRow = row; }
    }

    // pack: nonneg float bits are order-preserving as uint; low 32 = row
    // (equal distance -> smaller row wins, matching argmin's first-min)
    __shared__ unsigned long long skeys[4];
    if (lane == 0) {
        unsigned int bits = __float_as_uint(bestD);
        skeys[waveInBlock] =
            ((unsigned long long)bits << 32) | (unsigned int)bestRow;
    }
    __syncthreads();
    if (threadIdx.x == 0) {
        unsigned long long k = skeys[0];
        for (int i = 1; i < wavesPerBlk; ++i)
            if (skeys[i] < k) k = skeys[i];
        atomicMin(ws, k);
    }
}

// ---------------- kernel 2: fused neighborhood update ----------------
__global__ __launch_bounds__(256) void som_update_kernel(
        const float* __restrict__ x,
        const float* __restrict__ w,
        const int* __restrict__ it_p,
        const unsigned long long* __restrict__ ws,
        float* __restrict__ out) {
    const unsigned long long key = *ws;
    const int bmu = (int)(key & 0xFFFFFFFFull);
    const int bi  = bmu >> 9;        // / 512
    const int bj  = bmu & (NCOL - 1);

    const float lr       = 1.0f - (float)(*it_p) * 0.01f;   // it/NITER
    const float alpha_op = 0.3f * lr;
    const float sigma_op = 256.0f * lr;
    const float inv_s2   = 1.0f / (sigma_op * sigma_op);

    const int total4 = MN * (DIMC / 4);          // 16,777,216 float4s
    const int stride = gridDim.x * blockDim.x;

    for (int idx = blockIdx.x * blockDim.x + threadIdx.x; idx < total4;
         idx += stride) {
        const int row  = idx >> 6;               // DIM/4 = 64 float4 per row
        const int col4 = idx & 63;
        const int i = row >> 9;
        const int j = row & (NCOL - 1);
        const float di = (float)(i - bi);
        const float dj = (float)(j - bj);
        const float f  = alpha_op * __expf(-(di * di + dj * dj) * inv_s2);

        const float4 wv = reinterpret_cast<const float4*>(w)[idx];
        const float4 xv = reinterpret_cast<const float4*>(x)[col4];
        float4 o;
        o.x = wv.x + f * (xv.x - wv.x);
        o.y = wv.y + f * (xv.y - wv.y);
        o.z = wv.z + f * (xv.z - wv.z);
        o.w = wv.w + f * (xv.w - wv.w);
        reinterpret_cast<float4*>(out)[idx] = o;
    }
}

extern "C" void kernel_launch(void* const* d_in, const int* in_sizes, int n_in,
                              void* d_out, int out_size, void* d_ws, size_t ws_size,
                              hipStream_t stream) {
    const float* x = (const float*)d_in[0];
    const float* w = (const float*)d_in[1];
    const int*   it = (const int*)d_in[2];
    float* out = (float*)d_out;
    unsigned long long* ws = (unsigned long long*)d_ws;

    som_init_ws<<<1, 1, 0, stream>>>(ws);

    // BMU pass: 2048 blocks x 256 thr = 8192 waves, 32 rows/wave
    som_bmu_kernel<<<2048, 256, 0, stream>>>(x, w, ws);

    // Update pass: grid-stride over 16.7M float4s
    som_update_kernel<<<2048, 256, 0, stream>>>(x, w, it, ws, out);
}

// Round 3
// 135.067 us; speedup vs baseline: 1.3050x; 1.3050x over previous
//
#include <hip/hip_runtime.h>

// SOM update, M=N=512, DIM=256 (=64 float4), NITER=100, ALPHA=0.3, SIGMA=256.
// locations[row] = (row >> 9, row & 511)

#define MN   (512 * 512)
#define NCOL 512

typedef float vfloat4 __attribute__((ext_vector_type(4)));  // native vec for nontemporal builtin

// ---------------- kernel 0: init scratch key ----------------
__global__ void som_init_ws(unsigned long long* __restrict__ ws) {
    *ws = 0xFFFFFFFFFFFFFFFFull;
}

// ---------------- kernel 1: BMU argmin ----------------
// 16 lanes per row, 4 rows per wave iteration. Lane (16*sub + c) accumulates
// chunks k=0..3 of row (4*G+sub): elements [k*64 + c*4, +4).
// Per 4 rows: one 4-step shfl_xor butterfly within 16-lane groups.
// Packed key (distbits<<32 | row) -> min == first-occurrence argmin.
__global__ __launch_bounds__(256) void som_bmu_kernel(
        const float* __restrict__ x,
        const float* __restrict__ w,
        unsigned long long* __restrict__ ws) {
    const int lane        = threadIdx.x & 63;
    const int sub         = lane >> 4;     // row within 4-row group
    const int c           = lane & 15;     // 16B chunk within row
    const int waveInBlock = threadIdx.x >> 6;
    const int wavesPerBlk = blockDim.x >> 6;            // 4
    const int waveId      = blockIdx.x * wavesPerBlk + waveInBlock;
    const int nWaves      = gridDim.x * wavesPerBlk;    // 8192

    // x fragments this lane needs: x[k*64 + c*4 .. +4)
    float4 xv[4];
    #pragma unroll
    for (int k = 0; k < 4; ++k)
        xv[k] = reinterpret_cast<const float4*>(x)[k * 16 + c];

    unsigned long long bestKey = 0xFFFFFFFFFFFFFFFFull;

    for (int G = waveId; G < MN / 4; G += nWaves) {     // 8 iterations
        const int row = G * 4 + sub;
        const float4* wr = reinterpret_cast<const float4*>(w + (size_t)row * 256);
        float s = 0.0f;
        #pragma unroll
        for (int k = 0; k < 4; ++k) {
            const float4 wv = wr[k * 16 + c];
            const float d0 = xv[k].x - wv.x;
            const float d1 = xv[k].y - wv.y;
            const float d2 = xv[k].z - wv.z;
            const float d3 = xv[k].w - wv.w;
            s += d0 * d0 + d1 * d1 + d2 * d2 + d3 * d3;
        }
        // butterfly within 16-lane group: all lanes get the row's sum,
        // bitwise-identical across lanes (symmetric pair adds)
        #pragma unroll
        for (int m = 1; m < 16; m <<= 1) s += __shfl_xor(s, m);

        const unsigned long long key =
            ((unsigned long long)__float_as_uint(s) << 32) | (unsigned int)row;
        if (key < bestKey) bestKey = key;
    }

    // reduce the 4 row-groups across the wave
    #pragma unroll
    for (int m = 16; m < 64; m <<= 1) {
        const unsigned long long o = __shfl_xor(bestKey, m);
        if (o < bestKey) bestKey = o;
    }

    __shared__ unsigned long long skeys[4];
    if (lane == 0) skeys[waveInBlock] = bestKey;
    __syncthreads();
    if (threadIdx.x == 0) {
        unsigned long long k = skeys[0];
        #pragma unroll
        for (int i = 1; i < 4; ++i)
            if (skeys[i] < k) k = skeys[i];
        // cheap pre-check cuts same-address atomic serialization
        if (k < *(volatile unsigned long long*)ws) atomicMin(ws, k);
    }
}

// ---------------- kernel 2: fused neighborhood update ----------------
// One wave per row: 64 lanes x float4 = the full 1KB row, f computed once.
// Nontemporal stores for `out` (never re-read) to keep `w` resident in L3.
__global__ __launch_bounds__(256) void som_update_kernel(
        const float* __restrict__ x,
        const float* __restrict__ w,
        const int* __restrict__ it_p,
        const unsigned long long* __restrict__ ws,
        float* __restrict__ out) {
    const unsigned long long key = *ws;
    const int bmu = (int)(key & 0xFFFFFFFFull);
    const int bi  = bmu >> 9;
    const int bj  = bmu & (NCOL - 1);

    const float lr       = 1.0f - (float)(*it_p) * 0.01f;   // 1 - it/NITER
    const float alpha_op = 0.3f * lr;
    const float sigma_op = 256.0f * lr;
    const float inv_s2   = 1.0f / (sigma_op * sigma_op);

    const int lane   = threadIdx.x & 63;
    const int waveId = (int)((blockIdx.x * blockDim.x + threadIdx.x) >> 6);
    const int nWaves = (int)((gridDim.x * blockDim.x) >> 6);  // 8192

    const float4 xv = reinterpret_cast<const float4*>(x)[lane];

    for (int row = waveId; row < MN; row += nWaves) {         // 32 rows/wave
        const int i = row >> 9;
        const int j = row & (NCOL - 1);
        const float di = (float)(i - bi);
        const float dj = (float)(j - bj);
        const float f  = alpha_op * __expf(-(di * di + dj * dj) * inv_s2);

        const float4 wv =
            reinterpret_cast<const float4*>(w + (size_t)row * 256)[lane];
        vfloat4 o;
        o.x = wv.x + f * (xv.x - wv.x);
        o.y = wv.y + f * (xv.y - wv.y);
        o.z = wv.z + f * (xv.z - wv.z);
        o.w = wv.w + f * (xv.w - wv.w);
        __builtin_nontemporal_store(
            o, reinterpret_cast<vfloat4*>(out + (size_t)row * 256) + lane);
    }
}

extern "C" void kernel_launch(void* const* d_in, const int* in_sizes, int n_in,
                              void* d_out, int out_size, void* d_ws, size_t ws_size,
                              hipStream_t stream) {
    const float* x  = (const float*)d_in[0];
    const float* w  = (const float*)d_in[1];
    const int*   it = (const int*)d_in[2];
    float* out = (float*)d_out;
    unsigned long long* ws = (unsigned long long*)d_ws;

    som_init_ws<<<1, 1, 0, stream>>>(ws);

    // BMU: 2048 blocks x 4 waves = 8192 waves, 32 waves/CU
    som_bmu_kernel<<<2048, 256, 0, stream>>>(x, w, ws);

    // Update: 8192 waves, one row (1KB) per wave iteration
    som_update_kernel<<<2048, 256, 0, stream>>>(x, w, it, ws, out);
}

// Round 4
// 134.874 us; speedup vs baseline: 1.3069x; 1.0014x over previous
//
#include <hip/hip_runtime.h>

// SOM update, M=N=512, DIM=256 (=64 float4), NITER=100, ALPHA=0.3, SIGMA=256.
// locations[row] = (row >> 9, row & 511)

#define MN   (512 * 512)
#define NCOL 512

typedef float vfloat4 __attribute__((ext_vector_type(4)));  // native vec for nontemporal builtin

// ---------------- kernel 0: init scratch key ----------------
__global__ void som_init_ws(unsigned long long* __restrict__ ws) {
    *ws = 0xFFFFFFFFFFFFFFFFull;
}

// ---------------- kernel 1: BMU argmin ----------------
// 16 lanes per row, 4 rows per wave iteration. Lane (16*sub + c) accumulates
// chunks k=0..3 of row (4*G+sub): elements [k*64 + c*4, +4).
// Per 4 rows: one 4-step shfl_xor butterfly within 16-lane groups.
// Packed key (distbits<<32 | row) -> min == first-occurrence argmin.
__global__ __launch_bounds__(256) void som_bmu_kernel(
        const float* __restrict__ x,
        const float* __restrict__ w,
        unsigned long long* __restrict__ ws) {
    const int lane        = threadIdx.x & 63;
    const int sub         = lane >> 4;     // row within 4-row group
    const int c           = lane & 15;     // 16B chunk within row
    const int waveInBlock = threadIdx.x >> 6;
    const int wavesPerBlk = blockDim.x >> 6;            // 4
    const int waveId      = blockIdx.x * wavesPerBlk + waveInBlock;
    const int nWaves      = gridDim.x * wavesPerBlk;    // 8192

    // x fragments this lane needs: x[k*64 + c*4 .. +4)
    float4 xv[4];
    #pragma unroll
    for (int k = 0; k < 4; ++k)
        xv[k] = reinterpret_cast<const float4*>(x)[k * 16 + c];

    unsigned long long bestKey = 0xFFFFFFFFFFFFFFFFull;

    for (int G = waveId; G < MN / 4; G += nWaves) {     // 8 iterations
        const int row = G * 4 + sub;
        const float4* wr = reinterpret_cast<const float4*>(w + (size_t)row * 256);
        float s = 0.0f;
        #pragma unroll
        for (int k = 0; k < 4; ++k) {
            const float4 wv = wr[k * 16 + c];
            const float d0 = xv[k].x - wv.x;
            const float d1 = xv[k].y - wv.y;
            const float d2 = xv[k].z - wv.z;
            const float d3 = xv[k].w - wv.w;
            s += d0 * d0 + d1 * d1 + d2 * d2 + d3 * d3;
        }
        // butterfly within 16-lane group: all lanes get the row's sum,
        // bitwise-identical across lanes (symmetric pair adds)
        #pragma unroll
        for (int m = 1; m < 16; m <<= 1) s += __shfl_xor(s, m);

        const unsigned long long key =
            ((unsigned long long)__float_as_uint(s) << 32) | (unsigned int)row;
        if (key < bestKey) bestKey = key;
    }

    // reduce the 4 row-groups across the wave
    #pragma unroll
    for (int m = 16; m < 64; m <<= 1) {
        const unsigned long long o = __shfl_xor(bestKey, m);
        if (o < bestKey) bestKey = o;
    }

    __shared__ unsigned long long skeys[4];
    if (lane == 0) skeys[waveInBlock] = bestKey;
    __syncthreads();
    if (threadIdx.x == 0) {
        unsigned long long k = skeys[0];
        #pragma unroll
        for (int i = 1; i < 4; ++i)
            if (skeys[i] < k) k = skeys[i];
        // cheap pre-check cuts same-address atomic serialization
        if (k < *(volatile unsigned long long*)ws) atomicMin(ws, k);
    }
}

// ---------------- kernel 2: fused neighborhood update ----------------
// One wave per row; 4 rows in flight per iteration (explicit load/compute/
// store phases) so each CU keeps ~128 outstanding KB -> latency covered.
// Nontemporal stores for `out` (never re-read) keep `w` L3-resident.
__global__ __launch_bounds__(256) void som_update_kernel(
        const float* __restrict__ x,
        const float* __restrict__ w,
        const int* __restrict__ it_p,
        const unsigned long long* __restrict__ ws,
        float* __restrict__ out) {
    const unsigned long long key = *ws;
    const int bmu = (int)(key & 0xFFFFFFFFull);
    const int bi  = bmu >> 9;
    const int bj  = bmu & (NCOL - 1);

    const float lr       = 1.0f - (float)(*it_p) * 0.01f;   // 1 - it/NITER
    const float alpha_op = 0.3f * lr;
    const float sigma_op = 256.0f * lr;
    const float inv_s2   = 1.0f / (sigma_op * sigma_op);

    const int lane   = threadIdx.x & 63;
    const int waveId = (int)((blockIdx.x * blockDim.x + threadIdx.x) >> 6);
    const int nWaves = (int)((gridDim.x * blockDim.x) >> 6);  // 8192

    const float4 xv = reinterpret_cast<const float4*>(x)[lane];

    // 32 rows per wave total: 8 outer iterations x 4 rows in flight
    for (int base = waveId; base < MN; base += 4 * nWaves) {
        float4 wv[4];
        int    rows[4];
        #pragma unroll
        for (int k = 0; k < 4; ++k) {
            rows[k] = base + k * nWaves;
            wv[k] = reinterpret_cast<const float4*>(
                        w + (size_t)rows[k] * 256)[lane];
        }
        #pragma unroll
        for (int k = 0; k < 4; ++k) {
            const int row = rows[k];
            const int i = row >> 9;
            const int j = row & (NCOL - 1);
            const float di = (float)(i - bi);
            const float dj = (float)(j - bj);
            const float f  = alpha_op * __expf(-(di * di + dj * dj) * inv_s2);
            vfloat4 o;
            o.x = wv[k].x + f * (xv.x - wv[k].x);
            o.y = wv[k].y + f * (xv.y - wv[k].y);
            o.z = wv[k].z + f * (xv.z - wv[k].z);
            o.w = wv[k].w + f * (xv.w - wv[k].w);
            __builtin_nontemporal_store(
                o, reinterpret_cast<vfloat4*>(out + (size_t)row * 256) + lane);
        }
    }
}

extern "C" void kernel_launch(void* const* d_in, const int* in_sizes, int n_in,
                              void* d_out, int out_size, void* d_ws, size_t ws_size,
                              hipStream_t stream) {
    const float* x  = (const float*)d_in[0];
    const float* w  = (const float*)d_in[1];
    const int*   it = (const int*)d_in[2];
    float* out = (float*)d_out;
    unsigned long long* ws = (unsigned long long*)d_ws;

    som_init_ws<<<1, 1, 0, stream>>>(ws);

    // BMU: 2048 blocks x 4 waves = 8192 waves, 32 waves/CU
    som_bmu_kernel<<<2048, 256, 0, stream>>>(x, w, ws);

    // Update: 8192 waves, 4 rows (4KB) in flight per wave
    som_update_kernel<<<2048, 256, 0, stream>>>(x, w, it, ws, out);
}